// Round 10
// baseline (471.533 us; speedup 1.0000x reference)
//
#include <hip/hip_runtime.h>
#include <hip/hip_bf16.h>
#include <cmath>

typedef unsigned short u16;
typedef unsigned int u32;

using bf16x8 = __attribute__((ext_vector_type(8))) short;
using f32x4  = __attribute__((ext_vector_type(4))) float;

__device__ __forceinline__ float b2f(u16 u) {
  union { u32 i; float f; } x; x.i = ((u32)u) << 16; return x.f;
}
__device__ __forceinline__ u16 f2b(float f) {
  union { float f; u32 i; } x; x.f = f;
  u32 r = x.i + 0x7fffu + ((x.i >> 16) & 1u);
  return (u16)(r >> 16);
}
__device__ __forceinline__ u32 cvtpk(float lo, float hi) {
  u32 r;
  asm("v_cvt_pk_bf16_f32 %0, %1, %2" : "=v"(r) : "v"(lo), "v"(hi));
  return r;
}
__device__ __forceinline__ float vexp2(float x) {
  float r;
  asm("v_exp_f32 %0, %1" : "=v"(r) : "v"(x));
  return r;
}
__device__ __forceinline__ u32 bperm(int byteaddr, u32 v) {
  return __builtin_amdgcn_ds_bpermute(byteaddr, v);
}
__device__ __forceinline__ void gload_lds16(const u16* g, u16* l) {
  __builtin_amdgcn_global_load_lds(
      (const __attribute__((address_space(1))) unsigned int*)g,
      (__attribute__((address_space(3))) unsigned int*)l, 16, 0, 0);
}

// ---------------- fused weight cast fp32 -> bf16 (outputs contiguous) -----
__global__ __launch_bounds__(256) void castw(const float* __restrict__ qkvw,
                                             const float* __restrict__ projw,
                                             const float* __restrict__ fc1w,
                                             const float* __restrict__ fc2w,
                                             u16* __restrict__ o) {
  int i = blockIdx.x * 256 + threadIdx.x;  // < 786432
  const float* src;
  int off;
  if (i < 196608)      { src = qkvw;  off = 0; }
  else if (i < 262144) { src = projw; off = 196608; }
  else if (i < 524288) { src = fc1w;  off = 262144; }
  else                 { src = fc2w;  off = 524288; }
  o[i] = f2b(src[i - off]);
}

// ------- combined (bias+mask)*log2e, tile-blocked [64 sl][25 qt][25 t][16 lm]
// [16 kloc] bf16 (one contiguous 512B tile per wave read) + per-row max.
__global__ __launch_bounds__(256) void bias_k(const float* __restrict__ rpb,
                                              u16* __restrict__ biasB,
                                              float* __restrict__ rowmax) {
  const int b = blockIdx.x;  // sl*25 + qt
  const int sl = b / 25, qt = b - sl * 25;
  const int head = sl & 7, cls = sl >> 3;
  const int tb = (cls >> 2) & 1, hb = (cls >> 1) & 1, wb = cls & 1;
  const int tid = threadIdx.x;
  const int lm = tid >> 4, kl = tid & 15;
  int q = qt * 16 + lm; if (q > 391) q = 391;
  const int ti = q / 49, rem = q - ti * 49, hi = rem / 7, wi = rem - hi * 7;
  const int cq = ti * 169 + hi * 13 + wi;
  const int rtq = tb ? (ti < 4 ? 1 : 2) : 0;
  const int rhq = hb ? (hi < 4 ? 1 : 2) : 0;
  const int rwq = wb ? (wi < 4 ? 1 : 2) : 0;
  const int labq = rtq * 9 + rhq * 3 + rwq;
  float mx = -3e38f;
  u16* ob = biasB + (size_t)b * 6400 + tid;
  for (int t = 0; t < 25; t++) {
    int k = t * 16 + kl;
    float v;
    if (k < 392) {
      int tk = k / 49, rk = k - tk * 49, hk = rk / 7, wk = rk - hk * 7;
      int ck = tk * 169 + hk * 13 + wk;
      float bv = rpb[(cq - ck + 1267) * 8 + head];
      int rt = tb ? (tk < 4 ? 1 : 2) : 0;
      int rh = hb ? (hk < 4 ? 1 : 2) : 0;
      int rw = wb ? (wk < 4 ? 1 : 2) : 0;
      if (rt * 9 + rh * 3 + rw != labq) bv -= 100.f;
      v = bv * 1.4426950408889634f;
      mx = fmaxf(mx, v);
    } else {
      v = -2081.f;  // pad keys: exp2 -> exactly 0
    }
    ob[t * 256] = f2b(v);
  }
  mx = fmaxf(mx, __shfl_xor(mx, 1, 64));
  mx = fmaxf(mx, __shfl_xor(mx, 2, 64));
  mx = fmaxf(mx, __shfl_xor(mx, 4, 64));
  mx = fmaxf(mx, __shfl_xor(mx, 8, 64));
  if (kl == 0) rowmax[sl * 392 + q] = mx;
}

// ---------------- LayerNorm (+ optional roll+window-partition gather) ------
__global__ __launch_bounds__(256) void ln_k(const float* __restrict__ src,
                                            const float* __restrict__ g,
                                            const float* __restrict__ b,
                                            u16* __restrict__ dst, int shifted) {
  const int wid = threadIdx.x >> 6, lane = threadIdx.x & 63;
  const int row = blockIdx.x * 4 + wid;
  int srow;
  if (shifted) {
    int widx = row / 392, n = row - widx * 392;
    int wt = widx >> 6, wh = (widx >> 3) & 7, ww = widx & 7;
    int ti = n / 49, rem = n - ti * 49, hi = rem / 7, wi = rem - hi * 7;
    int t = (wt * 8 + ti + 4) & 15;
    int h = wh * 7 + hi + 3; if (h >= 56) h -= 56;
    int w = ww * 7 + wi + 3; if (w >= 56) w -= 56;
    srow = (t * 56 + h) * 56 + w;
  } else {
    srow = row;
  }
  float4 v = *(const float4*)(src + (size_t)srow * 256 + lane * 4);
  float s = v.x + v.y + v.z + v.w;
  float sq = v.x * v.x + v.y * v.y + v.z * v.z + v.w * v.w;
  for (int o = 1; o < 64; o <<= 1) {
    s += __shfl_xor(s, o, 64);
    sq += __shfl_xor(sq, o, 64);
  }
  float mu = s * (1.0f / 256.0f);
  float rstd = rsqrtf(sq * (1.0f / 256.0f) - mu * mu + 1e-5f);
  float4 gg = *(const float4*)(g + lane * 4);
  float4 bb = *(const float4*)(b + lane * 4);
  ushort4 ov;
  ov.x = f2b((v.x - mu) * rstd * gg.x + bb.x);
  ov.y = f2b((v.y - mu) * rstd * gg.y + bb.y);
  ov.z = f2b((v.z - mu) * rstd * gg.z + bb.z);
  ov.w = f2b((v.w - mu) * rstd * gg.w + bb.w);
  *(ushort4*)(dst + (size_t)row * 256 + lane * 4) = ov;
}

// ---------------- MFMA GEMM: C = A(MxK) @ B(NxK)^T -----------------------
// TM=256 x BN=128, BK=32, 512 threads / 8 waves, double-buffered LDS (48KB),
// 2-phase: STAGE(next) issued BEFORE compute(cur), one drain+barrier per tile.
template <int EPI>
__global__ __launch_bounds__(512) void gemm_k(const u16* __restrict__ A,
                                              const u16* __restrict__ Bw,
                                              int K, int tilesN,
                                              const float* __restrict__ bias,
                                              u16* __restrict__ outb,
                                              float* __restrict__ outf,
                                              const float* __restrict__ res,
                                              float qscale) {
  __shared__ __align__(16) u16 As[2][256 * 32];
  __shared__ __align__(16) u16 Bs[2][128 * 32];
  const int tid = threadIdx.x;
  const int swzb = ((int)blockIdx.x & 7) * ((int)gridDim.x >> 3) +
                   ((int)blockIdx.x >> 3);
  const int tm = swzb / tilesN, tn = swzb - tm * tilesN;
  const int wid = tid >> 6, lane = tid & 63;
  const int wm = wid >> 1, wn = wid & 1;
  const int lm = lane & 15, lk = lane >> 4;
  f32x4 acc[4][4] = {};
  const u16* Ap = A + (size_t)tm * 256 * K;
  const u16* Bp = Bw + (size_t)tn * 128 * K;

  const int sA0 = wid * 128;
  const int sB0 = wid * 64;
  const int nt = K >> 5;

#define STAGE(bufi, kk)                                                       \
  {                                                                           \
    int S = sA0 + lane, r = S >> 2, cs = S & 3;                               \
    gload_lds16(Ap + (size_t)r * K + (kk) + ((cs ^ ((r >> 1) & 3)) << 3),     \
                &As[bufi][sA0 * 8]);                                          \
    S = sA0 + 64 + lane; r = S >> 2; cs = S & 3;                              \
    gload_lds16(Ap + (size_t)r * K + (kk) + ((cs ^ ((r >> 1) & 3)) << 3),     \
                &As[bufi][(sA0 + 64) * 8]);                                   \
    S = sB0 + lane; r = S >> 2; cs = S & 3;                                   \
    gload_lds16(Bp + (size_t)r * K + (kk) + ((cs ^ ((r >> 1) & 3)) << 3),     \
                &Bs[bufi][sB0 * 8]);                                          \
  }

  STAGE(0, 0);
  __syncthreads();
  for (int t = 0; t < nt; t++) {
    const int cur = t & 1;
    if (t + 1 < nt) STAGE(cur ^ 1, (t + 1) << 5);
    bf16x8 af[4], bfr[4];
#pragma unroll
    for (int f = 0; f < 4; f++) {
      int ra = wm * 64 + f * 16 + lm;
      int rb = wn * 64 + f * 16 + lm;
      af[f] = *(const bf16x8*)((const char*)&As[cur][0] + ra * 64 +
                               ((lk ^ ((ra >> 1) & 3)) << 4));
      bfr[f] = *(const bf16x8*)((const char*)&Bs[cur][0] + rb * 64 +
                                ((lk ^ ((rb >> 1) & 3)) << 4));
    }
#pragma unroll
    for (int fm = 0; fm < 4; fm++)
#pragma unroll
      for (int fn = 0; fn < 4; fn++)
        acc[fm][fn] = __builtin_amdgcn_mfma_f32_16x16x32_bf16(
            af[fm], bfr[fn], acc[fm][fn], 0, 0, 0);
    __syncthreads();
  }
#undef STAGE

  const int rbase = tm * 256 + wm * 64, cbase = tn * 128 + wn * 64;
#pragma unroll
  for (int fm = 0; fm < 4; fm++) {
#pragma unroll
    for (int fn = 0; fn < 4; fn++) {
      const int col = cbase + fn * 16 + lm;
#pragma unroll
      for (int r = 0; r < 4; r++) {
        const int row = rbase + fm * 16 + lk * 4 + r;
        float v = acc[fm][fn][r] + bias[col];
        if (EPI == 0) {
          int s = col >> 8, rem = col & 255, head = rem >> 5, d = rem & 31;
          int widx = row / 392, n = row - widx * 392;
          size_t o;
          if (s == 2) {
            o = 25690112u + (((size_t)(widx * 8 + head)) * 32 + d) * 400 + n;
          } else {
            if (s == 0) v *= qscale;
            o = (size_t)s * 12845056u +
                (((size_t)(widx * 8 + head)) * 392 + n) * 32 + d;
          }
          outb[o] = f2b(v);
        } else if (EPI == 1) {
          int widx = row / 392, n = row - widx * 392;
          int wt = widx >> 6, wh = (widx >> 3) & 7, ww = widx & 7;
          int ti = n / 49, rem2 = n - ti * 49, hi = rem2 / 7, wi = rem2 - hi * 7;
          int t = (wt * 8 + ti + 4) & 15;
          int h = wh * 7 + hi + 3; if (h >= 56) h -= 56;
          int w = ww * 7 + wi + 3; if (w >= 56) w -= 56;
          size_t dr = ((size_t)(t * 56 + h)) * 56 + w;
          outf[dr * 256 + col] = res[dr * 256 + col] + v;
        } else if (EPI == 2) {
          float gv = 0.5f * v * (1.0f + erff(v * 0.70710678f));
          outb[(size_t)row * 1024 + col] = f2b(gv);
        } else {
          outf[(size_t)row * 256 + col] = res[(size_t)row * 256 + col] + v;
        }
      }
    }
  }
}

// ---------------- MFMA windowed attention, block per (window, head) -------
// 256 thr / 4 waves. LDS: K [400 rows][64B swz] @0 (25600) + V^T [32][848]
// @25600 (27136) -> 52736 B => 3 blocks/CU. P path fully in-register:
// S^T lane layout -> PV A-frag via 8 ds_bpermute + 4 selects per 32-key
// chunk (no Pq LDS, no lgkmcnt sync points).
__global__ __launch_bounds__(256, 3) void attn_k(
    const u16* __restrict__ qg, const u16* __restrict__ kg,
    const u16* __restrict__ vTg, const u16* __restrict__ biasB,
    const float* __restrict__ rowmax, u16* __restrict__ attno) {
  __shared__ __align__(16) char lds[52736];
  const int bid = blockIdx.x;  // widx*8 + head
  const int widx = bid >> 3;
  const int tid = threadIdx.x;
  const size_t base = (size_t)bid * 12544;
  const int tb = (widx >> 6) & 1;
  const int hb = (((widx >> 3) & 7) == 7) ? 1 : 0;
  const int wb = ((widx & 7) == 7) ? 1 : 0;
  const int sl = (tb * 4 + hb * 2 + wb) * 8 + (bid & 7);
  const int VOFF = 25600;

#pragma unroll
  for (int i = 0; i < 6; i++) {
    int s = i * 256 + tid, r = s >> 2, cs = s & 3;
    gload_lds16(kg + base + r * 32 + ((cs ^ ((r >> 1) & 3)) << 3),
                (u16*)(lds + (size_t)(i * 256 + (tid & ~63)) * 16));
  }
  if (tid < 32) {
    int s = 1536 + tid, r = s >> 2, cs = s & 3;
    gload_lds16(kg + base + r * 32 + ((cs ^ ((r >> 1) & 3)) << 3),
                (u16*)(lds + (size_t)1536 * 16));
  }
  if (tid < 128) ((u32*)(lds + 25088))[tid] = 0u;  // zero K pad rows 392..399
  {
    const u16* vsrc = vTg + (size_t)bid * 12800;
    for (int idx = tid; idx < 3200; idx += 256) {
      int d = idx / 100, c4 = idx - d * 100;
      *(ushort4*)(lds + VOFF + d * 848 + c4 * 8) =
          *(const ushort4*)(vsrc + d * 400 + c4 * 4);
    }
    for (int idx = tid; idx < 512; idx += 256) {
      int d = idx >> 4, e = idx & 15;
      *(u16*)(lds + VOFF + d * 848 + 800 + e * 2) = 0;
    }
  }
  __syncthreads();

  const int w = tid >> 6, lane = tid & 63;
  const int g = lane >> 4, lm = lane & 15;
  const int kswz = ((lm >> 1) & 3);
  // bpermute source byte-addr: lane ((g&1)*32 + lm), word2/3 source +16 lanes
  const int srcA = (((lane >> 4) & 1) << 7) + (lm << 2);
  const bool hi = (g >= 2);

  for (int qt = w; qt < 25; qt += 4) {
    const int q = qt * 16 + lm;
    const int qr = q < 391 ? q : 391;
    bf16x8 qf = *(const bf16x8*)(qg + base + (size_t)qr * 32 + g * 8);
    const u16* bp = biasB + ((size_t)(sl * 25 + qt) * 25) * 256 + lm * 16 + 4 * g;
    const float rmb = rowmax[sl * 392 + qr];
    f32x4 st[25];
#pragma unroll
    for (int t = 0; t < 25; t++) {
      ushort4 bb = *(const ushort4*)(bp + t * 256);
      f32x4 bacc = {b2f(bb.x), b2f(bb.y), b2f(bb.z), b2f(bb.w)};
      bf16x8 kf = *(const bf16x8*)(lds + (16 * t + lm) * 64 + ((g ^ kswz) << 4));
      st[t] = __builtin_amdgcn_mfma_f32_16x16x32_bf16(kf, qf, bacc, 0, 0, 0);
    }
    float m = -3e38f;
#pragma unroll
    for (int t = 0; t < 25; t++)
      m = fmaxf(m, fmaxf(fmaxf(st[t][0], st[t][1]), fmaxf(st[t][2], st[t][3])));
    m = fmaxf(m, __shfl_xor(m, 16, 64));
    m = fmaxf(m, __shfl_xor(m, 32, 64));
    m += rmb;  // upper bound of max(S + bias)

    float sum = 0.f;
    f32x4 oa0 = {0.f, 0.f, 0.f, 0.f}, oa1 = {0.f, 0.f, 0.f, 0.f};
#pragma unroll
    for (int c = 0; c < 13; c++) {
      float e00 = vexp2(st[2 * c][0] - m), e01 = vexp2(st[2 * c][1] - m);
      float e02 = vexp2(st[2 * c][2] - m), e03 = vexp2(st[2 * c][3] - m);
      sum += (e00 + e01) + (e02 + e03);
      u32 a0 = cvtpk(e00, e01), a1 = cvtpk(e02, e03);
      u32 b0, b1;
      if (c < 12) {
        float e10 = vexp2(st[2 * c + 1][0] - m), e11 = vexp2(st[2 * c + 1][1] - m);
        float e12 = vexp2(st[2 * c + 1][2] - m), e13 = vexp2(st[2 * c + 1][3] - m);
        sum += (e10 + e11) + (e12 + e13);
        b0 = cvtpk(e10, e11);
        b1 = cvtpk(e12, e13);
      } else {
        b0 = 0u; b1 = 0u;  // keys 400..415
      }
      // compose P A-frag: word0/1 from lane srcA, word2/3 from srcA+16 lanes;
      // tiles 2c (g<2) vs 2c+1 (g>=2)
      u32 A0 = bperm(srcA, a0), B0 = bperm(srcA, b0);
      u32 A1 = bperm(srcA, a1), B1 = bperm(srcA, b1);
      u32 A2 = bperm(srcA + 64, a0), B2 = bperm(srcA + 64, b0);
      u32 A3 = bperm(srcA + 64, a1), B3 = bperm(srcA + 64, b1);
      union { u32 u[4]; bf16x8 v; } P;
      P.u[0] = hi ? B0 : A0;
      P.u[1] = hi ? B1 : A1;
      P.u[2] = hi ? B2 : A2;
      P.u[3] = hi ? B3 : A3;
      const char* vrow = lds + VOFF + 64 * c + 16 * g;
      bf16x8 v0 = *(const bf16x8*)(vrow + lm * 848);
      bf16x8 v1 = *(const bf16x8*)(vrow + (16 + lm) * 848);
      oa0 = __builtin_amdgcn_mfma_f32_16x16x32_bf16(P.v, v0, oa0, 0, 0, 0);
      oa1 = __builtin_amdgcn_mfma_f32_16x16x32_bf16(P.v, v1, oa1, 0, 0, 0);
    }
    sum += __shfl_xor(sum, 16, 64);
    sum += __shfl_xor(sum, 32, 64);
    const float inv = 1.f / sum;
#pragma unroll
    for (int r = 0; r < 4; r++) {
      int qq = qt * 16 + 4 * g + r;
      if (qq < 392) {
        u16* op = attno + ((size_t)(widx * 392 + qq)) * 256 + (bid & 7) * 32;
        op[lm] = f2b(oa0[r] * inv);
        op[16 + lm] = f2b(oa1[r] * inv);
      }
    }
  }
}

extern "C" void kernel_launch(void* const* d_in, const int* in_sizes, int n_in,
                              void* d_out, int out_size, void* d_ws,
                              size_t ws_size, hipStream_t stream) {
  const float* x     = (const float*)d_in[0];
  const float* n1g   = (const float*)d_in[1];
  const float* n1b   = (const float*)d_in[2];
  const float* qkvw  = (const float*)d_in[3];
  const float* qkvb  = (const float*)d_in[4];
  const float* rpb   = (const float*)d_in[5];
  const float* projw = (const float*)d_in[6];
  const float* projb = (const float*)d_in[7];
  const float* n2g   = (const float*)d_in[8];
  const float* n2b   = (const float*)d_in[9];
  const float* fc1w  = (const float*)d_in[10];
  const float* fc1b  = (const float*)d_in[11];
  const float* fc2w  = (const float*)d_in[12];
  const float* fc2b  = (const float*)d_in[13];

  const size_t NEED = 130547712;
  if (ws_size < NEED) return;

  char* ws = (char*)d_ws;
  u16* xw      = (u16*)(ws + 0LL);
  u16* qb      = (u16*)(ws + 25690112LL);
  u16* attno   = (u16*)(ws + 0LL);
  u16* hid     = (u16*)(ws + 0LL);
  u16* biasB   = (u16*)(ws + 103284736LL);
  float* rmx   = (float*)(ws + 123764736LL);
  u16* h2      = (u16*)(ws + 103284736LL);
  u16* wq      = (u16*)(ws + 128974848LL);
  u16* wp      = (u16*)(ws + 129368064LL);
  u16* w1      = (u16*)(ws + 129499136LL);
  u16* w2      = (u16*)(ws + 130023424LL);
  float* xres  = (float*)d_out;

  castw<<<3072, 256, 0, stream>>>(qkvw, projw, fc1w, fc2w, wq);
  bias_k<<<1600, 256, 0, stream>>>(rpb, biasB, rmx);

  ln_k<<<12544, 256, 0, stream>>>(x, n1g, n1b, xw, 1);
  gemm_k<0><<<196 * 6, 512, 0, stream>>>(
      xw, wq, 256, 6, qkvb, qb, nullptr, nullptr,
      0.17677669529663687f * 1.4426950408889634f);
  attn_k<<<1024, 256, 0, stream>>>(qb, qb + 12845056, qb + 2 * 12845056, biasB,
                                   rmx, attno);
  gemm_k<1><<<196 * 2, 512, 0, stream>>>(attno, wp, 256, 2, projb, nullptr,
                                         xres, x, 0.f);
  ln_k<<<12544, 256, 0, stream>>>(xres, n2g, n2b, h2, 0);
  gemm_k<2><<<196 * 8, 512, 0, stream>>>(h2, w1, 256, 8, fc1b, hid, nullptr,
                                         nullptr, 0.f);
  gemm_k<3><<<196 * 2, 512, 0, stream>>>(hid, w2, 1024, 2, fc2b, nullptr,
                                         (float*)d_out, xres, 0.f);
}

// Round 11
// 362.650 us; speedup vs baseline: 1.3002x; 1.3002x over previous
//
#include <hip/hip_runtime.h>
#include <hip/hip_bf16.h>
#include <cmath>

typedef unsigned short u16;
typedef unsigned int u32;

using bf16x8 = __attribute__((ext_vector_type(8))) short;
using f32x4  = __attribute__((ext_vector_type(4))) float;

__device__ __forceinline__ float b2f(u16 u) {
  union { u32 i; float f; } x; x.i = ((u32)u) << 16; return x.f;
}
__device__ __forceinline__ u16 f2b(float f) {
  union { float f; u32 i; } x; x.f = f;
  u32 r = x.i + 0x7fffu + ((x.i >> 16) & 1u);
  return (u16)(r >> 16);
}
__device__ __forceinline__ u32 cvtpk(float lo, float hi) {
  u32 r;
  asm("v_cvt_pk_bf16_f32 %0, %1, %2" : "=v"(r) : "v"(lo), "v"(hi));
  return r;
}
__device__ __forceinline__ float vexp2(float x) {
  float r;
  asm("v_exp_f32 %0, %1" : "=v"(r) : "v"(x));
  return r;
}
__device__ __forceinline__ void gload_lds16(const u16* g, u16* l) {
  __builtin_amdgcn_global_load_lds(
      (const __attribute__((address_space(1))) unsigned int*)g,
      (__attribute__((address_space(3))) unsigned int*)l, 16, 0, 0);
}

// ---------------- fused weight cast fp32 -> bf16 (outputs contiguous) -----
__global__ __launch_bounds__(256) void castw(const float* __restrict__ qkvw,
                                             const float* __restrict__ projw,
                                             const float* __restrict__ fc1w,
                                             const float* __restrict__ fc2w,
                                             u16* __restrict__ o) {
  int i = blockIdx.x * 256 + threadIdx.x;  // < 786432
  const float* src;
  int off;
  if (i < 196608)      { src = qkvw;  off = 0; }
  else if (i < 262144) { src = projw; off = 196608; }
  else if (i < 524288) { src = fc1w;  off = 262144; }
  else                 { src = fc2w;  off = 524288; }
  o[i] = f2b(src[i - off]);
}

// ------- combined (bias+mask)*log2e, tile-blocked [64 sl][25 qt][25 t][16 lm]
// [16 kloc] bf16 + per-row max.
__global__ __launch_bounds__(256) void bias_k(const float* __restrict__ rpb,
                                              u16* __restrict__ biasB,
                                              float* __restrict__ rowmax) {
  const int b = blockIdx.x;  // sl*25 + qt
  const int sl = b / 25, qt = b - sl * 25;
  const int head = sl & 7, cls = sl >> 3;
  const int tb = (cls >> 2) & 1, hb = (cls >> 1) & 1, wb = cls & 1;
  const int tid = threadIdx.x;
  const int lm = tid >> 4, kl = tid & 15;
  int q = qt * 16 + lm; if (q > 391) q = 391;
  const int ti = q / 49, rem = q - ti * 49, hi = rem / 7, wi = rem - hi * 7;
  const int cq = ti * 169 + hi * 13 + wi;
  const int rtq = tb ? (ti < 4 ? 1 : 2) : 0;
  const int rhq = hb ? (hi < 4 ? 1 : 2) : 0;
  const int rwq = wb ? (wi < 4 ? 1 : 2) : 0;
  const int labq = rtq * 9 + rhq * 3 + rwq;
  float mx = -3e38f;
  u16* ob = biasB + (size_t)b * 6400 + tid;
  for (int t = 0; t < 25; t++) {
    int k = t * 16 + kl;
    float v;
    if (k < 392) {
      int tk = k / 49, rk = k - tk * 49, hk = rk / 7, wk = rk - hk * 7;
      int ck = tk * 169 + hk * 13 + wk;
      float bv = rpb[(cq - ck + 1267) * 8 + head];
      int rt = tb ? (tk < 4 ? 1 : 2) : 0;
      int rh = hb ? (hk < 4 ? 1 : 2) : 0;
      int rw = wb ? (wk < 4 ? 1 : 2) : 0;
      if (rt * 9 + rh * 3 + rw != labq) bv -= 100.f;
      v = bv * 1.4426950408889634f;
      mx = fmaxf(mx, v);
    } else {
      v = -2081.f;  // pad keys: exp2 -> exactly 0
    }
    ob[t * 256] = f2b(v);
  }
  mx = fmaxf(mx, __shfl_xor(mx, 1, 64));
  mx = fmaxf(mx, __shfl_xor(mx, 2, 64));
  mx = fmaxf(mx, __shfl_xor(mx, 4, 64));
  mx = fmaxf(mx, __shfl_xor(mx, 8, 64));
  if (kl == 0) rowmax[sl * 392 + q] = mx;
}

// ---------------- LayerNorm (+ roll+window-partition gather), LN1 ---------
__global__ __launch_bounds__(256) void ln_k(const float* __restrict__ src,
                                            const float* __restrict__ g,
                                            const float* __restrict__ b,
                                            u16* __restrict__ dst, int shifted) {
  const int wid = threadIdx.x >> 6, lane = threadIdx.x & 63;
  const int row = blockIdx.x * 4 + wid;
  int srow;
  if (shifted) {
    int widx = row / 392, n = row - widx * 392;
    int wt = widx >> 6, wh = (widx >> 3) & 7, ww = widx & 7;
    int ti = n / 49, rem = n - ti * 49, hi = rem / 7, wi = rem - hi * 7;
    int t = (wt * 8 + ti + 4) & 15;
    int h = wh * 7 + hi + 3; if (h >= 56) h -= 56;
    int w = ww * 7 + wi + 3; if (w >= 56) w -= 56;
    srow = (t * 56 + h) * 56 + w;
  } else {
    srow = row;
  }
  float4 v = *(const float4*)(src + (size_t)srow * 256 + lane * 4);
  float s = v.x + v.y + v.z + v.w;
  float sq = v.x * v.x + v.y * v.y + v.z * v.z + v.w * v.w;
  for (int o = 1; o < 64; o <<= 1) {
    s += __shfl_xor(s, o, 64);
    sq += __shfl_xor(sq, o, 64);
  }
  float mu = s * (1.0f / 256.0f);
  float rstd = rsqrtf(sq * (1.0f / 256.0f) - mu * mu + 1e-5f);
  float4 gg = *(const float4*)(g + lane * 4);
  float4 bb = *(const float4*)(b + lane * 4);
  ushort4 ov;
  ov.x = f2b((v.x - mu) * rstd * gg.x + bb.x);
  ov.y = f2b((v.y - mu) * rstd * gg.y + bb.y);
  ov.z = f2b((v.z - mu) * rstd * gg.z + bb.z);
  ov.w = f2b((v.w - mu) * rstd * gg.w + bb.w);
  *(ushort4*)(dst + (size_t)row * 256 + lane * 4) = ov;
}

// ---------------- MFMA GEMM: C = A(MxK) @ B(NxK)^T (EPI 0=qkv, 1=proj) ----
// TM=256 x BN=128, BK=32, 512 thr / 8 waves, dbuf LDS, 2-phase prefetch.
template <int EPI>
__global__ __launch_bounds__(512) void gemm_k(const u16* __restrict__ A,
                                              const u16* __restrict__ Bw,
                                              int K, int tilesN,
                                              const float* __restrict__ bias,
                                              u16* __restrict__ outb,
                                              float* __restrict__ outf,
                                              const float* __restrict__ res,
                                              float qscale) {
  __shared__ __align__(16) u16 As[2][256 * 32];
  __shared__ __align__(16) u16 Bs[2][128 * 32];
  const int tid = threadIdx.x;
  const int swzb = ((int)blockIdx.x & 7) * ((int)gridDim.x >> 3) +
                   ((int)blockIdx.x >> 3);
  const int tm = swzb / tilesN, tn = swzb - tm * tilesN;
  const int wid = tid >> 6, lane = tid & 63;
  const int wm = wid >> 1, wn = wid & 1;
  const int lm = lane & 15, lk = lane >> 4;
  f32x4 acc[4][4] = {};
  const u16* Ap = A + (size_t)tm * 256 * K;
  const u16* Bp = Bw + (size_t)tn * 128 * K;

  const int sA0 = wid * 128;
  const int sB0 = wid * 64;
  const int nt = K >> 5;

#define STAGE(bufi, kk)                                                       \
  {                                                                           \
    int S = sA0 + lane, r = S >> 2, cs = S & 3;                               \
    gload_lds16(Ap + (size_t)r * K + (kk) + ((cs ^ ((r >> 1) & 3)) << 3),     \
                &As[bufi][sA0 * 8]);                                          \
    S = sA0 + 64 + lane; r = S >> 2; cs = S & 3;                              \
    gload_lds16(Ap + (size_t)r * K + (kk) + ((cs ^ ((r >> 1) & 3)) << 3),     \
                &As[bufi][(sA0 + 64) * 8]);                                   \
    S = sB0 + lane; r = S >> 2; cs = S & 3;                                   \
    gload_lds16(Bp + (size_t)r * K + (kk) + ((cs ^ ((r >> 1) & 3)) << 3),     \
                &Bs[bufi][sB0 * 8]);                                          \
  }

  STAGE(0, 0);
  __syncthreads();
  for (int t = 0; t < nt; t++) {
    const int cur = t & 1;
    if (t + 1 < nt) STAGE(cur ^ 1, (t + 1) << 5);
    bf16x8 af[4], bfr[4];
#pragma unroll
    for (int f = 0; f < 4; f++) {
      int ra = wm * 64 + f * 16 + lm;
      int rb = wn * 64 + f * 16 + lm;
      af[f] = *(const bf16x8*)((const char*)&As[cur][0] + ra * 64 +
                               ((lk ^ ((ra >> 1) & 3)) << 4));
      bfr[f] = *(const bf16x8*)((const char*)&Bs[cur][0] + rb * 64 +
                                ((lk ^ ((rb >> 1) & 3)) << 4));
    }
#pragma unroll
    for (int fm = 0; fm < 4; fm++)
#pragma unroll
      for (int fn = 0; fn < 4; fn++)
        acc[fm][fn] = __builtin_amdgcn_mfma_f32_16x16x32_bf16(
            af[fm], bfr[fn], acc[fm][fn], 0, 0, 0);
    __syncthreads();
  }
#undef STAGE

  const int rbase = tm * 256 + wm * 64, cbase = tn * 128 + wn * 64;
#pragma unroll
  for (int fm = 0; fm < 4; fm++) {
#pragma unroll
    for (int fn = 0; fn < 4; fn++) {
      const int col = cbase + fn * 16 + lm;
#pragma unroll
      for (int r = 0; r < 4; r++) {
        const int row = rbase + fm * 16 + lk * 4 + r;
        float v = acc[fm][fn][r] + bias[col];
        if (EPI == 0) {
          int s = col >> 8, rem = col & 255, head = rem >> 5, d = rem & 31;
          int widx = row / 392, n = row - widx * 392;
          size_t o;
          if (s == 2) {
            o = 25690112u + (((size_t)(widx * 8 + head)) * 32 + d) * 400 + n;
          } else {
            if (s == 0) v *= qscale;
            o = (size_t)s * 12845056u +
                (((size_t)(widx * 8 + head)) * 392 + n) * 32 + d;
          }
          outb[o] = f2b(v);
        } else {
          int widx = row / 392, n = row - widx * 392;
          int wt = widx >> 6, wh = (widx >> 3) & 7, ww = widx & 7;
          int ti = n / 49, rem2 = n - ti * 49, hi = rem2 / 7, wi = rem2 - hi * 7;
          int t = (wt * 8 + ti + 4) & 15;
          int h = wh * 7 + hi + 3; if (h >= 56) h -= 56;
          int w = ww * 7 + wi + 3; if (w >= 56) w -= 56;
          size_t dr = ((size_t)(t * 56 + h)) * 56 + w;
          outf[dr * 256 + col] = res[dr * 256 + col] + v;
        }
      }
    }
  }
}

// ---------------- fused MLP: out = xres + fc2(gelu(fc1(LN(xres)))) --------
// 64-row tile per block, 256 thr / 4 waves. LDS 64KB: A (LN-out, 32K,
// swizzled) + Hs (h chunk, 16K, swizzled) + Ws (W staging, 16K, swizzled).
// Weights stream from L2 (1MB hot). acc2 = 64 VGPR lives across the block.
__global__ __launch_bounds__(256) void mlp_k(const float* __restrict__ xres,
                                             const u16* __restrict__ w1,
                                             const float* __restrict__ b1,
                                             const u16* __restrict__ w2,
                                             const float* __restrict__ b2,
                                             const float* __restrict__ n2g,
                                             const float* __restrict__ n2b,
                                             float* __restrict__ out) {
  __shared__ __align__(16) char lds[65536];
  char* Abuf = lds;            // [64][512B], slot ^= row&7 (32 slots)
  char* Hs = lds + 32768;      // [64][256B], slot ^= row&7 (16 slots)
  u16* Ws = (u16*)(lds + 49152);  // staging, 64B rows, slot ^= row&3

  const int tid = threadIdx.x;
  const int swzb = ((int)blockIdx.x & 7) * ((int)gridDim.x >> 3) +
                   ((int)blockIdx.x >> 3);
  const int row0 = swzb * 64;
  const int w = tid >> 6, lane = tid & 63;
  const int lm = lane & 15, g = lane >> 4;

  // ---- LN2 phase: xres rows -> bf16 A tile (swizzled)
  {
    float4 gg = *(const float4*)(n2g + lane * 4);
    float4 bb = *(const float4*)(n2b + lane * 4);
    for (int rr = 0; rr < 16; rr++) {
      int r = w * 16 + rr;
      float4 v = *(const float4*)(xres + (size_t)(row0 + r) * 256 + lane * 4);
      float s = v.x + v.y + v.z + v.w;
      float sq = v.x * v.x + v.y * v.y + v.z * v.z + v.w * v.w;
      for (int o = 1; o < 64; o <<= 1) {
        s += __shfl_xor(s, o, 64);
        sq += __shfl_xor(sq, o, 64);
      }
      float mu = s * (1.0f / 256.0f);
      float rstd = rsqrtf(sq * (1.0f / 256.0f) - mu * mu + 1e-5f);
      uint2 pp;
      pp.x = cvtpk((v.x - mu) * rstd * gg.x + bb.x,
                   (v.y - mu) * rstd * gg.y + bb.y);
      pp.y = cvtpk((v.z - mu) * rstd * gg.z + bb.z,
                   (v.w - mu) * rstd * gg.w + bb.w);
      *(uint2*)(Abuf + r * 512 + (((lane >> 1) ^ (r & 7)) << 4) +
                ((lane & 1) << 3)) = pp;
    }
  }

  f32x4 acc2[4][4] = {};
  for (int j = 0; j < 8; j++) {
    // ---- gemm1: h = A(64x256) @ W1_j(128x256)^T, wave w -> cols w*32..+31
    f32x4 acc1[4][2] = {};
    for (int ks = 0; ks < 8; ks++) {
      __syncthreads();  // Ws free + (ks==0) Hs prev chunk reads done
      {  // stage W1_j[:, ks*32..+32): 512 slots, 2/thread
        int i0 = w * 64 + lane;
#pragma unroll
        for (int it = 0; it < 2; it++) {
          int idx = it * 256 + i0, r = idx >> 2, s = idx & 3;
          gload_lds16(w1 + (size_t)(j * 128 + r) * 256 + ks * 32 +
                          ((s ^ (r & 3)) << 3),
                      Ws + (size_t)(it * 256 + w * 64) * 8);
        }
      }
      __syncthreads();
      bf16x8 af[4], bfr[2];
#pragma unroll
      for (int f = 0; f < 4; f++) {
        int ra = f * 16 + lm;
        af[f] = *(const bf16x8*)(Abuf + ra * 512 +
                                 (((ks * 4 + g) ^ (ra & 7)) << 4));
      }
#pragma unroll
      for (int f = 0; f < 2; f++) {
        int rb = w * 32 + f * 16 + lm;
        bfr[f] = *(const bf16x8*)((const char*)Ws + rb * 64 +
                                  ((g ^ (rb & 3)) << 4));
      }
#pragma unroll
      for (int fm = 0; fm < 4; fm++)
#pragma unroll
        for (int fn = 0; fn < 2; fn++)
          acc1[fm][fn] = __builtin_amdgcn_mfma_f32_16x16x32_bf16(
              af[fm], bfr[fn], acc1[fm][fn], 0, 0, 0);
    }
    // ---- bias + exact GELU + write h to Hs (swizzled)
#pragma unroll
    for (int fn = 0; fn < 2; fn++) {
      int col = w * 32 + fn * 16 + lm;
      float bv = b1[j * 128 + col];
#pragma unroll
      for (int fm = 0; fm < 4; fm++) {
#pragma unroll
        for (int r = 0; r < 4; r++) {
          float v = acc1[fm][fn][r] + bv;
          float gv = 0.5f * v * (1.0f + erff(v * 0.70710678f));
          int row = fm * 16 + g * 4 + r;
          *(u16*)(Hs + row * 256 + ((((col >> 3) ^ (row & 7))) << 4) +
                  ((col & 7) << 1)) = f2b(gv);
        }
      }
    }
    // ---- gemm2: acc2 += h(64x128) @ W2_j(256x128)^T, wave w -> cols w*64
    for (int ks = 0; ks < 4; ks++) {
      __syncthreads();  // h writes visible (ks==0) + Ws free
      {  // stage W2[:, j*128+ks*32..+32): 1024 slots, 4/thread
        int i0 = w * 64 + lane;
#pragma unroll
        for (int it = 0; it < 4; it++) {
          int idx = it * 256 + i0, r = idx >> 2, s = idx & 3;
          gload_lds16(w2 + (size_t)r * 1024 + j * 128 + ks * 32 +
                          ((s ^ (r & 3)) << 3),
                      Ws + (size_t)(it * 256 + w * 64) * 8);
        }
      }
      __syncthreads();
      bf16x8 af[4], bfr[4];
#pragma unroll
      for (int f = 0; f < 4; f++) {
        int ra = f * 16 + lm;
        af[f] = *(const bf16x8*)(Hs + ra * 256 +
                                 (((ks * 4 + g) ^ (ra & 7)) << 4));
        int rb = w * 64 + f * 16 + lm;
        bfr[f] = *(const bf16x8*)((const char*)Ws + rb * 64 +
                                  ((g ^ (rb & 3)) << 4));
      }
#pragma unroll
      for (int fm = 0; fm < 4; fm++)
#pragma unroll
        for (int fn = 0; fn < 4; fn++)
          acc2[fm][fn] = __builtin_amdgcn_mfma_f32_16x16x32_bf16(
              af[fm], bfr[fn], acc2[fm][fn], 0, 0, 0);
    }
  }
  // ---- epilogue: out = xres + acc2 + b2
#pragma unroll
  for (int fm = 0; fm < 4; fm++) {
#pragma unroll
    for (int fn = 0; fn < 4; fn++) {
      int col = w * 64 + fn * 16 + lm;
      float bv = b2[col];
#pragma unroll
      for (int r = 0; r < 4; r++) {
        size_t o = (size_t)(row0 + fm * 16 + g * 4 + r) * 256 + col;
        out[o] = xres[o] + acc2[fm][fn][r] + bv;
      }
    }
  }
}

// ---------------- MFMA windowed attention (round-9 proven version) --------
__global__ __launch_bounds__(256) void attn_k(const u16* __restrict__ qg,
                                              const u16* __restrict__ kg,
                                              const u16* __restrict__ vTg,
                                              const u16* __restrict__ biasB,
                                              const float* __restrict__ rowmax,
                                              u16* __restrict__ attno) {
  __shared__ __align__(16) char lds[60928];
  const int bid = blockIdx.x;  // widx*8 + head
  const int widx = bid >> 3;
  const int tid = threadIdx.x;
  const size_t base = (size_t)bid * 12544;
  const int tb = (widx >> 6) & 1;
  const int hb = (((widx >> 3) & 7) == 7) ? 1 : 0;
  const int wb = ((widx & 7) == 7) ? 1 : 0;
  const int sl = (tb * 4 + hb * 2 + wb) * 8 + (bid & 7);
  const int VOFF = 25600;

#pragma unroll
  for (int i = 0; i < 6; i++) {
    int s = i * 256 + tid, r = s >> 2, cs = s & 3;
    gload_lds16(kg + base + r * 32 + ((cs ^ ((r >> 1) & 3)) << 3),
                (u16*)(lds + (size_t)(i * 256 + (tid & ~63)) * 16));
  }
  if (tid < 32) {
    int s = 1536 + tid, r = s >> 2, cs = s & 3;
    gload_lds16(kg + base + r * 32 + ((cs ^ ((r >> 1) & 3)) << 3),
                (u16*)(lds + (size_t)1536 * 16));
  }
  if (tid < 128) ((u32*)(lds + 25088))[tid] = 0u;
  {
    const u16* vsrc = vTg + (size_t)bid * 12800;
    for (int idx = tid; idx < 3200; idx += 256) {
      int d = idx / 100, c4 = idx - d * 100;
      *(ushort4*)(lds + VOFF + d * 848 + c4 * 8) =
          *(const ushort4*)(vsrc + d * 400 + c4 * 4);
    }
    for (int idx = tid; idx < 512; idx += 256) {
      int d = idx >> 4, e = idx & 15;
      *(u16*)(lds + VOFF + d * 848 + 800 + e * 2) = 0;
    }
  }
  __syncthreads();

  const int w = tid >> 6, lane = tid & 63;
  const int g = lane >> 4, lm = lane & 15;
  char* PqW = lds + 52736 + w * 2048 + lm * 128;
  const int swz = (lm & 7) << 4;
  const int kswz = ((lm >> 1) & 3);

  for (int qt = w; qt < 25; qt += 4) {
    const int q = qt * 16 + lm;
    const int qr = q < 391 ? q : 391;
    bf16x8 qf = *(const bf16x8*)(qg + base + (size_t)qr * 32 + g * 8);
    const u16* bp = biasB + ((size_t)(sl * 25 + qt) * 25) * 256 + lm * 16 + 4 * g;
    const float rmb = rowmax[sl * 392 + qr];
    f32x4 st[25];
#pragma unroll
    for (int t = 0; t < 25; t++) {
      ushort4 bb = *(const ushort4*)(bp + t * 256);
      f32x4 bacc = {b2f(bb.x), b2f(bb.y), b2f(bb.z), b2f(bb.w)};
      bf16x8 kf = *(const bf16x8*)(lds + (16 * t + lm) * 64 + ((g ^ kswz) << 4));
      st[t] = __builtin_amdgcn_mfma_f32_16x16x32_bf16(kf, qf, bacc, 0, 0, 0);
    }
    float m = -3e38f;
#pragma unroll
    for (int t = 0; t < 25; t++)
      m = fmaxf(m, fmaxf(fmaxf(st[t][0], st[t][1]), fmaxf(st[t][2], st[t][3])));
    m = fmaxf(m, __shfl_xor(m, 16, 64));
    m = fmaxf(m, __shfl_xor(m, 32, 64));
    m += rmb;

    float sum = 0.f;
    f32x4 oa0 = {0.f, 0.f, 0.f, 0.f}, oa1 = {0.f, 0.f, 0.f, 0.f};
#pragma unroll
    for (int p = 0; p < 6; p++) {
#pragma unroll
      for (int tl = 0; tl < 4; tl++) {
        int t = 4 * p + tl;
        float e0 = vexp2(st[t][0] - m), e1 = vexp2(st[t][1] - m);
        float e2 = vexp2(st[t][2] - m), e3 = vexp2(st[t][3] - m);
        sum += (e0 + e1) + (e2 + e3);
        uint2 pp;
        pp.x = cvtpk(e0, e1);
        pp.y = cvtpk(e2, e3);
        *(uint2*)(PqW + ((32 * tl + 8 * g) ^ swz)) = pp;
      }
      asm volatile("s_waitcnt lgkmcnt(0)" ::: "memory");
      __builtin_amdgcn_sched_barrier(0);
#pragma unroll
      for (int cl = 0; cl < 2; cl++) {
        int c = 2 * p + cl;
        bf16x8 pf = *(const bf16x8*)(PqW + ((64 * cl + 16 * g) ^ swz));
        const char* vrow = lds + VOFF + 64 * c + 16 * g;
        bf16x8 v0 = *(const bf16x8*)(vrow + lm * 848);
        bf16x8 v1 = *(const bf16x8*)(vrow + (16 + lm) * 848);
        oa0 = __builtin_amdgcn_mfma_f32_16x16x32_bf16(pf, v0, oa0, 0, 0, 0);
        oa1 = __builtin_amdgcn_mfma_f32_16x16x32_bf16(pf, v1, oa1, 0, 0, 0);
      }
      __builtin_amdgcn_sched_barrier(0);
    }
    {
      float e0 = vexp2(st[24][0] - m), e1 = vexp2(st[24][1] - m);
      float e2 = vexp2(st[24][2] - m), e3 = vexp2(st[24][3] - m);
      sum += (e0 + e1) + (e2 + e3);
      uint2 pp;
      pp.x = cvtpk(e0, e1);
      pp.y = cvtpk(e2, e3);
      *(uint2*)(PqW + ((8 * g) ^ swz)) = pp;
      uint2 zz; zz.x = 0u; zz.y = 0u;
      *(uint2*)(PqW + ((32 + 8 * g) ^ swz)) = zz;
      asm volatile("s_waitcnt lgkmcnt(0)" ::: "memory");
      __builtin_amdgcn_sched_barrier(0);
      bf16x8 pf = *(const bf16x8*)(PqW + ((16 * g) ^ swz));
      const char* vrow = lds + VOFF + 64 * 12 + 16 * g;
      bf16x8 v0 = *(const bf16x8*)(vrow + lm * 848);
      bf16x8 v1 = *(const bf16x8*)(vrow + (16 + lm) * 848);
      oa0 = __builtin_amdgcn_mfma_f32_16x16x32_bf16(pf, v0, oa0, 0, 0, 0);
      oa1 = __builtin_amdgcn_mfma_f32_16x16x32_bf16(pf, v1, oa1, 0, 0, 0);
      __builtin_amdgcn_sched_barrier(0);
    }
    sum += __shfl_xor(sum, 16, 64);
    sum += __shfl_xor(sum, 32, 64);
    const float inv = 1.f / sum;
#pragma unroll
    for (int r = 0; r < 4; r++) {
      int qq = qt * 16 + 4 * g + r;
      if (qq < 392) {
        u16* op = attno + ((size_t)(widx * 392 + qq)) * 256 + (bid & 7) * 32;
        op[lm] = f2b(oa0[r] * inv);
        op[16 + lm] = f2b(oa1[r] * inv);
      }
    }
  }
}

extern "C" void kernel_launch(void* const* d_in, const int* in_sizes, int n_in,
                              void* d_out, int out_size, void* d_ws,
                              size_t ws_size, hipStream_t stream) {
  const float* x     = (const float*)d_in[0];
  const float* n1g   = (const float*)d_in[1];
  const float* n1b   = (const float*)d_in[2];
  const float* qkvw  = (const float*)d_in[3];
  const float* qkvb  = (const float*)d_in[4];
  const float* rpb   = (const float*)d_in[5];
  const float* projw = (const float*)d_in[6];
  const float* projb = (const float*)d_in[7];
  const float* n2g   = (const float*)d_in[8];
  const float* n2b   = (const float*)d_in[9];
  const float* fc1w  = (const float*)d_in[10];
  const float* fc1b  = (const float*)d_in[11];
  const float* fc2w  = (const float*)d_in[12];
  const float* fc2b  = (const float*)d_in[13];

  const size_t NEED = 130547712;
  if (ws_size < NEED) return;

  char* ws = (char*)d_ws;
  u16* xw      = (u16*)(ws + 0LL);
  u16* qb      = (u16*)(ws + 25690112LL);
  u16* attno   = (u16*)(ws + 0LL);
  u16* biasB   = (u16*)(ws + 103284736LL);
  float* rmx   = (float*)(ws + 123764736LL);
  u16* wq      = (u16*)(ws + 128974848LL);
  u16* wp      = (u16*)(ws + 129368064LL);
  u16* w1      = (u16*)(ws + 129499136LL);
  u16* w2      = (u16*)(ws + 130023424LL);
  float* xres  = (float*)d_out;

  castw<<<3072, 256, 0, stream>>>(qkvw, projw, fc1w, fc2w, wq);
  bias_k<<<1600, 256, 0, stream>>>(rpb, biasB, rmx);

  ln_k<<<12544, 256, 0, stream>>>(x, n1g, n1b, xw, 1);
  gemm_k<0><<<196 * 6, 512, 0, stream>>>(
      xw, wq, 256, 6, qkvb, qb, nullptr, nullptr,
      0.17677669529663687f * 1.4426950408889634f);
  attn_k<<<1024, 256, 0, stream>>>(qb, qb + 12845056, qb + 2 * 12845056, biasB,
                                   rmx, attno);
  gemm_k<1><<<196 * 2, 512, 0, stream>>>(attno, wp, 256, 2, projb, nullptr,
                                         xres, x, 0.f);
  mlp_k<<<784, 256, 0, stream>>>(xres, w1, fc1b, w2, fc2b, n2g, n2b,
                                 (float*)d_out);
}

// Round 12
// 330.466 us; speedup vs baseline: 1.4269x; 1.0974x over previous
//
#include <hip/hip_runtime.h>
#include <hip/hip_bf16.h>
#include <cmath>

typedef unsigned short u16;
typedef unsigned int u32;

using bf16x8 = __attribute__((ext_vector_type(8))) short;
using f32x4  = __attribute__((ext_vector_type(4))) float;

__device__ __forceinline__ float b2f(u16 u) {
  union { u32 i; float f; } x; x.i = ((u32)u) << 16; return x.f;
}
__device__ __forceinline__ u16 f2b(float f) {
  union { float f; u32 i; } x; x.f = f;
  u32 r = x.i + 0x7fffu + ((x.i >> 16) & 1u);
  return (u16)(r >> 16);
}
__device__ __forceinline__ u32 cvtpk(float lo, float hi) {
  u32 r;
  asm("v_cvt_pk_bf16_f32 %0, %1, %2" : "=v"(r) : "v"(lo), "v"(hi));
  return r;
}
__device__ __forceinline__ float vexp2(float x) {
  float r;
  asm("v_exp_f32 %0, %1" : "=v"(r) : "v"(x));
  return r;
}
__device__ __forceinline__ void gload_lds16(const u16* g, u16* l) {
  __builtin_amdgcn_global_load_lds(
      (const __attribute__((address_space(1))) unsigned int*)g,
      (__attribute__((address_space(3))) unsigned int*)l, 16, 0, 0);
}

// ---------------- fused weight cast fp32 -> bf16 (outputs contiguous) -----
__global__ __launch_bounds__(256) void castw(const float* __restrict__ qkvw,
                                             const float* __restrict__ projw,
                                             const float* __restrict__ fc1w,
                                             const float* __restrict__ fc2w,
                                             u16* __restrict__ o) {
  int i = blockIdx.x * 256 + threadIdx.x;  // < 786432
  const float* src;
  int off;
  if (i < 196608)      { src = qkvw;  off = 0; }
  else if (i < 262144) { src = projw; off = 196608; }
  else if (i < 524288) { src = fc1w;  off = 262144; }
  else                 { src = fc2w;  off = 524288; }
  o[i] = f2b(src[i - off]);
}

// ------- combined (bias+mask)*log2e, tile-blocked [64 sl][25 qt][25 t][16 lm]
// [16 kloc] bf16 + per-row max.
__global__ __launch_bounds__(256) void bias_k(const float* __restrict__ rpb,
                                              u16* __restrict__ biasB,
                                              float* __restrict__ rowmax) {
  const int b = blockIdx.x;  // sl*25 + qt
  const int sl = b / 25, qt = b - sl * 25;
  const int head = sl & 7, cls = sl >> 3;
  const int tb = (cls >> 2) & 1, hb = (cls >> 1) & 1, wb = cls & 1;
  const int tid = threadIdx.x;
  const int lm = tid >> 4, kl = tid & 15;
  int q = qt * 16 + lm; if (q > 391) q = 391;
  const int ti = q / 49, rem = q - ti * 49, hi = rem / 7, wi = rem - hi * 7;
  const int cq = ti * 169 + hi * 13 + wi;
  const int rtq = tb ? (ti < 4 ? 1 : 2) : 0;
  const int rhq = hb ? (hi < 4 ? 1 : 2) : 0;
  const int rwq = wb ? (wi < 4 ? 1 : 2) : 0;
  const int labq = rtq * 9 + rhq * 3 + rwq;
  float mx = -3e38f;
  u16* ob = biasB + (size_t)b * 6400 + tid;
  for (int t = 0; t < 25; t++) {
    int k = t * 16 + kl;
    float v;
    if (k < 392) {
      int tk = k / 49, rk = k - tk * 49, hk = rk / 7, wk = rk - hk * 7;
      int ck = tk * 169 + hk * 13 + wk;
      float bv = rpb[(cq - ck + 1267) * 8 + head];
      int rt = tb ? (tk < 4 ? 1 : 2) : 0;
      int rh = hb ? (hk < 4 ? 1 : 2) : 0;
      int rw = wb ? (wk < 4 ? 1 : 2) : 0;
      if (rt * 9 + rh * 3 + rw != labq) bv -= 100.f;
      v = bv * 1.4426950408889634f;
      mx = fmaxf(mx, v);
    } else {
      v = -2081.f;  // pad keys 392..399: exp2 -> exactly 0
    }
    ob[t * 256] = f2b(v);
  }
  mx = fmaxf(mx, __shfl_xor(mx, 1, 64));
  mx = fmaxf(mx, __shfl_xor(mx, 2, 64));
  mx = fmaxf(mx, __shfl_xor(mx, 4, 64));
  mx = fmaxf(mx, __shfl_xor(mx, 8, 64));
  if (kl == 0) rowmax[sl * 392 + q] = mx;
}

// ---------------- LayerNorm (+ optional roll+window-partition gather) ------
__global__ __launch_bounds__(256) void ln_k(const float* __restrict__ src,
                                            const float* __restrict__ g,
                                            const float* __restrict__ b,
                                            u16* __restrict__ dst, int shifted) {
  const int wid = threadIdx.x >> 6, lane = threadIdx.x & 63;
  const int row = blockIdx.x * 4 + wid;
  int srow;
  if (shifted) {
    int widx = row / 392, n = row - widx * 392;
    int wt = widx >> 6, wh = (widx >> 3) & 7, ww = widx & 7;
    int ti = n / 49, rem = n - ti * 49, hi = rem / 7, wi = rem - hi * 7;
    int t = (wt * 8 + ti + 4) & 15;
    int h = wh * 7 + hi + 3; if (h >= 56) h -= 56;
    int w = ww * 7 + wi + 3; if (w >= 56) w -= 56;
    srow = (t * 56 + h) * 56 + w;
  } else {
    srow = row;
  }
  float4 v = *(const float4*)(src + (size_t)srow * 256 + lane * 4);
  float s = v.x + v.y + v.z + v.w;
  float sq = v.x * v.x + v.y * v.y + v.z * v.z + v.w * v.w;
  for (int o = 1; o < 64; o <<= 1) {
    s += __shfl_xor(s, o, 64);
    sq += __shfl_xor(sq, o, 64);
  }
  float mu = s * (1.0f / 256.0f);
  float rstd = rsqrtf(sq * (1.0f / 256.0f) - mu * mu + 1e-5f);
  float4 gg = *(const float4*)(g + lane * 4);
  float4 bb = *(const float4*)(b + lane * 4);
  ushort4 ov;
  ov.x = f2b((v.x - mu) * rstd * gg.x + bb.x);
  ov.y = f2b((v.y - mu) * rstd * gg.y + bb.y);
  ov.z = f2b((v.z - mu) * rstd * gg.z + bb.z);
  ov.w = f2b((v.w - mu) * rstd * gg.w + bb.w);
  *(ushort4*)(dst + (size_t)row * 256 + lane * 4) = ov;
}

// ---------------- MFMA GEMM: C = A(MxK) @ B(NxK)^T -----------------------
// TM=256 x BN=128, BK=32, 512 thr / 8 waves, dbuf LDS, 2-phase prefetch.
// EPI: 0=qkv scatter (+vT), 1=proj+residual scatter, 2=fc1 gelu, 3=fc2+res.
template <int EPI>
__global__ __launch_bounds__(512) void gemm_k(const u16* __restrict__ A,
                                              const u16* __restrict__ Bw,
                                              int K, int tilesN,
                                              const float* __restrict__ bias,
                                              u16* __restrict__ outb,
                                              float* __restrict__ outf,
                                              const float* __restrict__ res,
                                              float qscale) {
  __shared__ __align__(16) u16 As[2][256 * 32];
  __shared__ __align__(16) u16 Bs[2][128 * 32];
  const int tid = threadIdx.x;
  const int swzb = ((int)blockIdx.x & 7) * ((int)gridDim.x >> 3) +
                   ((int)blockIdx.x >> 3);
  const int tm = swzb / tilesN, tn = swzb - tm * tilesN;
  const int wid = tid >> 6, lane = tid & 63;
  const int wm = wid >> 1, wn = wid & 1;
  const int lm = lane & 15, lk = lane >> 4;
  f32x4 acc[4][4] = {};
  const u16* Ap = A + (size_t)tm * 256 * K;
  const u16* Bp = Bw + (size_t)tn * 128 * K;

  const int sA0 = wid * 128;
  const int sB0 = wid * 64;
  const int nt = K >> 5;

#define STAGE(bufi, kk)                                                       \
  {                                                                           \
    int S = sA0 + lane, r = S >> 2, cs = S & 3;                               \
    gload_lds16(Ap + (size_t)r * K + (kk) + ((cs ^ ((r >> 1) & 3)) << 3),     \
                &As[bufi][sA0 * 8]);                                          \
    S = sA0 + 64 + lane; r = S >> 2; cs = S & 3;                              \
    gload_lds16(Ap + (size_t)r * K + (kk) + ((cs ^ ((r >> 1) & 3)) << 3),     \
                &As[bufi][(sA0 + 64) * 8]);                                   \
    S = sB0 + lane; r = S >> 2; cs = S & 3;                                   \
    gload_lds16(Bp + (size_t)r * K + (kk) + ((cs ^ ((r >> 1) & 3)) << 3),     \
                &Bs[bufi][sB0 * 8]);                                          \
  }

  STAGE(0, 0);
  __syncthreads();
  for (int t = 0; t < nt; t++) {
    const int cur = t & 1;
    if (t + 1 < nt) STAGE(cur ^ 1, (t + 1) << 5);
    bf16x8 af[4], bfr[4];
#pragma unroll
    for (int f = 0; f < 4; f++) {
      int ra = wm * 64 + f * 16 + lm;
      int rb = wn * 64 + f * 16 + lm;
      af[f] = *(const bf16x8*)((const char*)&As[cur][0] + ra * 64 +
                               ((lk ^ ((ra >> 1) & 3)) << 4));
      bfr[f] = *(const bf16x8*)((const char*)&Bs[cur][0] + rb * 64 +
                                ((lk ^ ((rb >> 1) & 3)) << 4));
    }
#pragma unroll
    for (int fm = 0; fm < 4; fm++)
#pragma unroll
      for (int fn = 0; fn < 4; fn++)
        acc[fm][fn] = __builtin_amdgcn_mfma_f32_16x16x32_bf16(
            af[fm], bfr[fn], acc[fm][fn], 0, 0, 0);
    __syncthreads();
  }
#undef STAGE

  const int rbase = tm * 256 + wm * 64, cbase = tn * 128 + wn * 64;
#pragma unroll
  for (int fm = 0; fm < 4; fm++) {
#pragma unroll
    for (int fn = 0; fn < 4; fn++) {
      const int col = cbase + fn * 16 + lm;
#pragma unroll
      for (int r = 0; r < 4; r++) {
        const int row = rbase + fm * 16 + lk * 4 + r;
        float v = acc[fm][fn][r] + bias[col];
        if (EPI == 0) {
          int s = col >> 8, rem = col & 255, head = rem >> 5, d = rem & 31;
          int widx = row / 392, n = row - widx * 392;
          size_t o;
          if (s == 2) {
            o = 25690112u + (((size_t)(widx * 8 + head)) * 32 + d) * 400 + n;
          } else {
            if (s == 0) v *= qscale;
            o = (size_t)s * 12845056u +
                (((size_t)(widx * 8 + head)) * 392 + n) * 32 + d;
          }
          outb[o] = f2b(v);
        } else if (EPI == 1) {
          int widx = row / 392, n = row - widx * 392;
          int wt = widx >> 6, wh = (widx >> 3) & 7, ww = widx & 7;
          int ti = n / 49, rem2 = n - ti * 49, hi = rem2 / 7, wi = rem2 - hi * 7;
          int t = (wt * 8 + ti + 4) & 15;
          int h = wh * 7 + hi + 3; if (h >= 56) h -= 56;
          int w = ww * 7 + wi + 3; if (w >= 56) w -= 56;
          size_t dr = ((size_t)(t * 56 + h)) * 56 + w;
          outf[dr * 256 + col] = res[dr * 256 + col] + v;
        } else if (EPI == 2) {
          float gv = 0.5f * v * (1.0f + erff(v * 0.70710678f));
          outb[(size_t)row * 1024 + col] = f2b(gv);
        } else {
          outf[(size_t)row * 256 + col] = res[(size_t)row * 256 + col] + v;
        }
      }
    }
  }
}

// ---------------- MFMA windowed attention, block per (window, head) -------
// LDS diet for 3 blocks/CU: K [392][64B swz] @0 (25088) + V^T [32][784B]
// @25088 (25088) + Pq 4x1024 @50176 -> 54272 B. QK tile 24 rows 392..399
// duplicate rows 384..391 (lm&7) -> finite scores, killed by bias -2081
// (P = exactly 0). PV: 13 chunks of 32 keys; all out-of-range V reads
// multiply P=0.
__global__ __launch_bounds__(256) void attn_k(const u16* __restrict__ qg,
                                              const u16* __restrict__ kg,
                                              const u16* __restrict__ vTg,
                                              const u16* __restrict__ biasB,
                                              const float* __restrict__ rowmax,
                                              u16* __restrict__ attno) {
  __shared__ __align__(16) char lds[54272];
  const int bid = blockIdx.x;  // widx*8 + head
  const int widx = bid >> 3;
  const int tid = threadIdx.x;
  const size_t base = (size_t)bid * 12544;
  const int tb = (widx >> 6) & 1;
  const int hb = (((widx >> 3) & 7) == 7) ? 1 : 0;
  const int wb = ((widx & 7) == 7) ? 1 : 0;
  const int sl = (tb * 4 + hb * 2 + wb) * 8 + (bid & 7);
  const int VOFF = 25088;

  // --- stage K rows 0..391 via global_load_lds (pre-swizzled source)
#pragma unroll
  for (int i = 0; i < 6; i++) {
    int s = i * 256 + tid, r = s >> 2, cs = s & 3;
    gload_lds16(kg + base + r * 32 + ((cs ^ ((r >> 1) & 3)) << 3),
                (u16*)(lds + (size_t)(i * 256 + (tid & ~63)) * 16));
  }
  if (tid < 32) {
    int s = 1536 + tid, r = s >> 2, cs = s & 3;
    gload_lds16(kg + base + r * 32 + ((cs ^ ((r >> 1) & 3)) << 3),
                (u16*)(lds + (size_t)1536 * 16));
  }
  // --- stage V^T rows (784B each, 392 keys, coalesced)
  {
    const u16* vsrc = vTg + (size_t)bid * 12800;
    for (int idx = tid; idx < 3136; idx += 256) {
      int d = idx / 98, c4 = idx - d * 98;
      *(ushort4*)(lds + VOFF + d * 784 + c4 * 8) =
          *(const ushort4*)(vsrc + d * 400 + c4 * 4);
    }
  }
  __syncthreads();

  const int w = tid >> 6, lane = tid & 63;
  const int g = lane >> 4, lm = lane & 15;
  char* PqW = lds + 50176 + w * 1024 + lm * 64;
  const int swz = ((lm >> 1) & 3) << 4;
  const int kswz = ((lm >> 1) & 3);

  for (int qt = w; qt < 25; qt += 4) {
    const int q = qt * 16 + lm;
    const int qr = q < 391 ? q : 391;
    bf16x8 qf = *(const bf16x8*)(qg + base + (size_t)qr * 32 + g * 8);
    const u16* bp = biasB + ((size_t)(sl * 25 + qt) * 25) * 256 + lm * 16 + 4 * g;
    const float rmb = rowmax[sl * 392 + qr];
    f32x4 st[25];
#pragma unroll
    for (int t = 0; t < 25; t++) {
      ushort4 bb = *(const ushort4*)(bp + t * 256);
      f32x4 bacc = {b2f(bb.x), b2f(bb.y), b2f(bb.z), b2f(bb.w)};
      int kr = (t < 24) ? (16 * t + lm) : (384 + (lm & 7));
      bf16x8 kf = *(const bf16x8*)(lds + kr * 64 + ((g ^ kswz) << 4));
      st[t] = __builtin_amdgcn_mfma_f32_16x16x32_bf16(kf, qf, bacc, 0, 0, 0);
    }
    float m = -3e38f;
#pragma unroll
    for (int t = 0; t < 25; t++)
      m = fmaxf(m, fmaxf(fmaxf(st[t][0], st[t][1]), fmaxf(st[t][2], st[t][3])));
    m = fmaxf(m, __shfl_xor(m, 16, 64));
    m = fmaxf(m, __shfl_xor(m, 32, 64));
    m += rmb;  // upper bound of max(S + bias)

    float sum = 0.f;
    f32x4 oa0 = {0.f, 0.f, 0.f, 0.f}, oa1 = {0.f, 0.f, 0.f, 0.f};
#pragma unroll
    for (int c = 0; c < 13; c++) {
      {  // tile 2c -> Pq bytes 0..31
        int t = 2 * c;
        float e0 = vexp2(st[t][0] - m), e1 = vexp2(st[t][1] - m);
        float e2 = vexp2(st[t][2] - m), e3 = vexp2(st[t][3] - m);
        sum += (e0 + e1) + (e2 + e3);
        uint2 pp;
        pp.x = cvtpk(e0, e1);
        pp.y = cvtpk(e2, e3);
        *(uint2*)(PqW + ((8 * g) ^ swz)) = pp;
      }
      {  // tile 2c+1 -> Pq bytes 32..63 (zeros for c==12)
        uint2 pp;
        if (c < 12) {
          int t = 2 * c + 1;
          float e0 = vexp2(st[t][0] - m), e1 = vexp2(st[t][1] - m);
          float e2 = vexp2(st[t][2] - m), e3 = vexp2(st[t][3] - m);
          sum += (e0 + e1) + (e2 + e3);
          pp.x = cvtpk(e0, e1);
          pp.y = cvtpk(e2, e3);
        } else {
          pp.x = 0u; pp.y = 0u;
        }
        *(uint2*)(PqW + ((32 + 8 * g) ^ swz)) = pp;
      }
      asm volatile("s_waitcnt lgkmcnt(0)" ::: "memory");
      __builtin_amdgcn_sched_barrier(0);
      bf16x8 pf = *(const bf16x8*)(PqW + ((16 * g) ^ swz));
      const char* vrow = lds + VOFF + 64 * c + 16 * g;
      bf16x8 v0 = *(const bf16x8*)(vrow + lm * 784);
      bf16x8 v1 = *(const bf16x8*)(vrow + (16 + lm) * 784);
      oa0 = __builtin_amdgcn_mfma_f32_16x16x32_bf16(pf, v0, oa0, 0, 0, 0);
      oa1 = __builtin_amdgcn_mfma_f32_16x16x32_bf16(pf, v1, oa1, 0, 0, 0);
      __builtin_amdgcn_sched_barrier(0);
    }
    sum += __shfl_xor(sum, 16, 64);
    sum += __shfl_xor(sum, 32, 64);
    const float inv = 1.f / sum;
#pragma unroll
    for (int r = 0; r < 4; r++) {
      int qq = qt * 16 + 4 * g + r;
      if (qq < 392) {
        u16* op = attno + ((size_t)(widx * 392 + qq)) * 256 + (bid & 7) * 32;
        op[lm] = f2b(oa0[r] * inv);
        op[16 + lm] = f2b(oa1[r] * inv);
      }
    }
  }
}

extern "C" void kernel_launch(void* const* d_in, const int* in_sizes, int n_in,
                              void* d_out, int out_size, void* d_ws,
                              size_t ws_size, hipStream_t stream) {
  const float* x     = (const float*)d_in[0];
  const float* n1g   = (const float*)d_in[1];
  const float* n1b   = (const float*)d_in[2];
  const float* qkvw  = (const float*)d_in[3];
  const float* qkvb  = (const float*)d_in[4];
  const float* rpb   = (const float*)d_in[5];
  const float* projw = (const float*)d_in[6];
  const float* projb = (const float*)d_in[7];
  const float* n2g   = (const float*)d_in[8];
  const float* n2b   = (const float*)d_in[9];
  const float* fc1w  = (const float*)d_in[10];
  const float* fc1b  = (const float*)d_in[11];
  const float* fc2w  = (const float*)d_in[12];
  const float* fc2b  = (const float*)d_in[13];

  // Workspace (NEED = 130,547,712 B), lifetime-aliased:
  //  [0, 25.69M)        xw -> attno -> hid(low)
  //  [25.69M, 103.28M)  q,k,vT       -> hid(high)
  //  [103.28M, 123.87M) biasB+rowmax -> h2
  //  [128.97M, 130.55M) bf16 weights
  const size_t NEED = 130547712;
  if (ws_size < NEED) return;

  char* ws = (char*)d_ws;
  u16* xw      = (u16*)(ws + 0LL);
  u16* qb      = (u16*)(ws + 25690112LL);
  u16* attno   = (u16*)(ws + 0LL);
  u16* hid     = (u16*)(ws + 0LL);
  u16* biasB   = (u16*)(ws + 103284736LL);
  float* rmx   = (float*)(ws + 123764736LL);
  u16* h2      = (u16*)(ws + 103284736LL);
  u16* wq      = (u16*)(ws + 128974848LL);
  u16* wp      = (u16*)(ws + 129368064LL);
  u16* w1      = (u16*)(ws + 129499136LL);
  u16* w2      = (u16*)(ws + 130023424LL);
  float* xres  = (float*)d_out;

  castw<<<3072, 256, 0, stream>>>(qkvw, projw, fc1w, fc2w, wq);
  bias_k<<<1600, 256, 0, stream>>>(rpb, biasB, rmx);

  ln_k<<<12544, 256, 0, stream>>>(x, n1g, n1b, xw, 1);
  gemm_k<0><<<196 * 6, 512, 0, stream>>>(
      xw, wq, 256, 6, qkvb, qb, nullptr, nullptr,
      0.17677669529663687f * 1.4426950408889634f);
  attn_k<<<1024, 256, 0, stream>>>(qb, qb + 12845056, qb + 2 * 12845056, biasB,
                                   rmx, attno);
  gemm_k<1><<<196 * 2, 512, 0, stream>>>(attno, wp, 256, 2, projb, nullptr,
                                         xres, x, 0.f);
  ln_k<<<12544, 256, 0, stream>>>(xres, n2g, n2b, h2, 0);
  gemm_k<2><<<196 * 8, 512, 0, stream>>>(h2, w1, 256, 8, fc1b, hid, nullptr,
                                         nullptr, 0.f);
  gemm_k<3><<<196 * 2, 512, 0, stream>>>(hid, w2, 1024, 2, fc2b, nullptr,
                                         (float*)d_out, xres, 0.f);
}